// Round 1
// baseline (386.691 us; speedup 1.0000x reference)
//
#include <hip/hip_runtime.h>

typedef __attribute__((ext_vector_type(8))) short bf16x8;
typedef __attribute__((ext_vector_type(4))) short s16x4;
typedef __attribute__((ext_vector_type(4))) float f32x4;

#define MFMA(a, b, c) __builtin_amdgcn_mfma_f32_16x16x32_bf16((a), (b), (c), 0, 0, 0)
#define Q_SCALE 0.17677669529663687f /* 32^-0.5 */

__device__ __forceinline__ short f2bf(float f) {
  union { float f; unsigned u; } c; c.f = f;
  unsigned u = c.u;
  return (short)((u + 0x7FFFu + ((u >> 16) & 1u)) >> 16);  // RNE
}

// 8 bf16 from an 8B-aligned LDS address (stride is 16B*odd/2 in some layouts)
__device__ __forceinline__ bf16x8 ld8u(const short* p) {
  s16x4 lo = *(const s16x4*)p;
  s16x4 hi = *(const s16x4*)(p + 4);
  return __builtin_shufflevector(lo, hi, 0, 1, 2, 3, 4, 5, 6, 7);
}

// ---------------------------------------------------------------------------
// prep: bf16 weight copies + relative-position bias gathered in MFMA C-frag
// order: bias_frag[h][lane][mt][nt][reg]
// ---------------------------------------------------------------------------
__global__ void prep_kernel(const float* __restrict__ qkv_w,
                            const float* __restrict__ proj_w,
                            const float* __restrict__ tbl,
                            const int* __restrict__ ridx,
                            short* __restrict__ wq, short* __restrict__ wp,
                            float* __restrict__ bfr) {
  const int stride = gridDim.x * blockDim.x;
  const int tid = blockIdx.x * blockDim.x + threadIdx.x;
  for (int i = tid; i < 384 * 128; i += stride) wq[i] = f2bf(qkv_w[i]);
  for (int i = tid; i < 128 * 128; i += stride) wp[i] = f2bf(proj_w[i]);
  for (int i = tid; i < 4 * 64 * 64; i += stride) {
    int reg = i & 3, nt = (i >> 2) & 3, mt = (i >> 4) & 3;
    int lane = (i >> 6) & 63, h = i >> 12;
    int row = mt * 16 + (lane >> 4) * 4 + reg;
    int col = nt * 16 + (lane & 15);
    bfr[i] = tbl[ridx[row * 64 + col] * 4 + h];
  }
}

// ---------------------------------------------------------------------------
// fused window attention: one block (4 waves) per 8x8 window; wave = head
// LDS regions (bytes):
//   XS [64][136] bf16 @0      (17408)  x tile, token-major     | reused as P/AO
//   Q  [4][64][36] bf16 @17408 (18432)                          | reused by P
//   K  [4][64][36] bf16 @35840 (18432)
//   V  [4][32][68] bf16 @54272 (17408)  transposed [d][token]
//   P  [4][64][68] bf16 @0     (34816)  overlays XS+Q (dead)
//   AO [64][136]  bf16 @0      (17408)  overlays P heads 0-1 (dead)
// ---------------------------------------------------------------------------
__global__ __launch_bounds__(256, 2) void winattn_kernel(
    const float* __restrict__ x, const float* __restrict__ qkv_b,
    const float* __restrict__ proj_b, const short* __restrict__ wq,
    const short* __restrict__ wp, const float* __restrict__ bias_frag,
    float* __restrict__ out) {
  __shared__ char lds_raw[71680];
  short* XS = (short*)lds_raw;
  short* Q = (short*)(lds_raw + 17408);
  short* K = (short*)(lds_raw + 35840);
  short* V = (short*)(lds_raw + 54272);
  short* P = (short*)lds_raw;
  short* AO = (short*)lds_raw;

  const int tid = threadIdx.x;
  const int w = tid >> 6;  // wave id == head
  const int l = tid & 63;
  const int llo = l & 15, lhi = l >> 4;

  // XCD-bijective swizzle (8192 % 8 == 0): XCD k owns batch-image k's windows
  const int bid = blockIdx.x;
  const int wid = (bid & 7) * 1024 + (bid >> 3);
  const int b = wid >> 10;
  const int wy = (wid >> 5) & 31, wx = wid & 31;
  const int y0 = wy * 8, x0 = wx * 8;

  // ---- Phase 0: global x (f32) -> XS bf16 [token][channel]
  const float* xb = x + (size_t)b * 128 * 65536;
  for (int k = 0; k < 8; ++k) {
    int u = tid + k * 256;  // 0..2047 float4 units
    int c = u >> 4, i = (u >> 1) & 7, j4 = u & 1;
    f32x4 v4 = *(const f32x4*)(xb + (size_t)c * 65536 + (y0 + i) * 256 + x0 + j4 * 4);
    int t = i * 8 + j4 * 4;
    XS[(t + 0) * 136 + c] = f2bf(v4[0]);
    XS[(t + 1) * 136 + c] = f2bf(v4[1]);
    XS[(t + 2) * 136 + c] = f2bf(v4[2]);
    XS[(t + 3) * 136 + c] = f2bf(v4[3]);
  }
  __syncthreads();

  // ---- Phase 1: QKV GEMM  qkv[t][o] = sum_c XS[t][c] * qkv_w[o][c] + b[o]
  {
    bf16x8 xa[4][4];  // A-frags hoisted: [mt][ks]
    for (int mt = 0; mt < 4; ++mt)
      for (int ks = 0; ks < 4; ++ks)
        xa[mt][ks] = *(const bf16x8*)(XS + (mt * 16 + llo) * 136 + ks * 32 + lhi * 8);
    for (int nt = 0; nt < 6; ++nt) {
      const int o = w * 96 + nt * 16 + llo;
      f32x4 acc[4];
      for (int mt = 0; mt < 4; ++mt) acc[mt] = f32x4{0.f, 0.f, 0.f, 0.f};
      for (int ks = 0; ks < 4; ++ks) {
        bf16x8 bf = *(const bf16x8*)(wq + o * 128 + ks * 32 + lhi * 8);
        for (int mt = 0; mt < 4; ++mt) acc[mt] = MFMA(xa[mt][ks], bf, acc[mt]);
      }
      const float bias = qkv_b[o];
      const int sel = o >> 7, rem = o & 127, head = rem >> 5, d = rem & 31;
      for (int mt = 0; mt < 4; ++mt)
        for (int r = 0; r < 4; ++r) {
          const int t = mt * 16 + lhi * 4 + r;
          const float val = acc[mt][r] + bias;
          if (sel == 0)
            Q[head * 2304 + t * 36 + d] = f2bf(val * Q_SCALE);
          else if (sel == 1)
            K[head * 2304 + t * 36 + d] = f2bf(val);
          else
            V[head * 2176 + d * 68 + t] = f2bf(val);  // transposed
        }
    }
  }
  __syncthreads();

  // ---- Phase 2: dots = q k^T + bias (bias preloaded as accumulator)
  const int h = w;
  f32x4 dots[4][4];
  {
    bf16x8 qf[4], kf[4];
    const short* qh = Q + h * 2304;
    const short* kh = K + h * 2304;
    for (int mt = 0; mt < 4; ++mt) qf[mt] = ld8u(qh + (mt * 16 + llo) * 36 + lhi * 8);
    for (int nt = 0; nt < 4; ++nt) kf[nt] = ld8u(kh + (nt * 16 + llo) * 36 + lhi * 8);
    const float* bfr = bias_frag + (h * 64 + l) * 64;
    for (int mt = 0; mt < 4; ++mt)
      for (int nt = 0; nt < 4; ++nt)
        dots[mt][nt] = *(const f32x4*)(bfr + (mt * 4 + nt) * 4);
    for (int nt = 0; nt < 4; ++nt)
      for (int mt = 0; mt < 4; ++mt)
        dots[mt][nt] = MFMA(qf[mt], kf[nt], dots[mt][nt]);
  }
  __syncthreads();  // q,k now dead -> P region writable

  // ---- Phase 3: softmax over each row (held by 16 lanes x 4 local nt vals)
  short* ph = P + h * 4352;
  for (int mt = 0; mt < 4; ++mt)
    for (int r = 0; r < 4; ++r) {
      float m = fmaxf(fmaxf(dots[mt][0][r], dots[mt][1][r]),
                      fmaxf(dots[mt][2][r], dots[mt][3][r]));
      for (int off = 8; off; off >>= 1) m = fmaxf(m, __shfl_xor(m, off));
      const float p0 = __expf(dots[mt][0][r] - m);
      const float p1 = __expf(dots[mt][1][r] - m);
      const float p2 = __expf(dots[mt][2][r] - m);
      const float p3 = __expf(dots[mt][3][r] - m);
      float s = p0 + p1 + p2 + p3;
      for (int off = 8; off; off >>= 1) s += __shfl_xor(s, off);
      const float inv = 1.0f / s;
      short* prow = ph + (mt * 16 + lhi * 4 + r) * 68 + llo;
      prow[0] = f2bf(p0 * inv);
      prow[16] = f2bf(p1 * inv);
      prow[32] = f2bf(p2 * inv);
      prow[48] = f2bf(p3 * inv);
    }
  __syncthreads();

  // ---- Phase 4: out = P @ V   (M=64 tok, N=32 d, K=64 j)
  f32x4 oacc[4][2];
  for (int mt = 0; mt < 4; ++mt)
    for (int nv = 0; nv < 2; ++nv) oacc[mt][nv] = f32x4{0.f, 0.f, 0.f, 0.f};
  {
    const short* vh = V + h * 2176;
    for (int ks = 0; ks < 2; ++ks) {
      bf16x8 vf[2];
      for (int nv = 0; nv < 2; ++nv)
        vf[nv] = ld8u(vh + (nv * 16 + llo) * 68 + ks * 32 + lhi * 8);
      for (int mt = 0; mt < 4; ++mt) {
        bf16x8 pf = ld8u(ph + (mt * 16 + llo) * 68 + ks * 32 + lhi * 8);
        for (int nv = 0; nv < 2; ++nv) oacc[mt][nv] = MFMA(pf, vf[nv], oacc[mt][nv]);
      }
    }
  }
  __syncthreads();  // all P reads done -> AO region writable

  // ---- Phase 5: assemble AO[t][c] (c = h*32 + d), bf16
  for (int mt = 0; mt < 4; ++mt)
    for (int nv = 0; nv < 2; ++nv)
      for (int r = 0; r < 4; ++r) {
        const int t = mt * 16 + lhi * 4 + r;
        AO[t * 136 + h * 32 + nv * 16 + llo] = f2bf(oacc[mt][nv][r]);
      }
  __syncthreads();

  // ---- Phase 6: proj, computed transposed: C[ch][tok] for coalesced-ish
  // stores straight into (b,c,h,w).  A = proj_w rows, B = AO^T.
  f32x4 pacc[2][4];
  for (int mc = 0; mc < 2; ++mc)
    for (int ntt = 0; ntt < 4; ++ntt) pacc[mc][ntt] = f32x4{0.f, 0.f, 0.f, 0.f};
  for (int ks = 0; ks < 4; ++ks) {
    const int c0 = ks * 32 + lhi * 8;
    bf16x8 bfr2[4];
    for (int ntt = 0; ntt < 4; ++ntt)
      bfr2[ntt] = *(const bf16x8*)(AO + (ntt * 16 + llo) * 136 + c0);
    for (int mc = 0; mc < 2; ++mc) {
      bf16x8 af = *(const bf16x8*)(wp + (w * 32 + mc * 16 + llo) * 128 + c0);
      for (int ntt = 0; ntt < 4; ++ntt)
        pacc[mc][ntt] = MFMA(af, bfr2[ntt], pacc[mc][ntt]);
    }
  }
  float* ob = out + (size_t)b * 128 * 65536;
  for (int mc = 0; mc < 2; ++mc)
    for (int r = 0; r < 4; ++r) {
      const int ch = w * 32 + mc * 16 + lhi * 4 + r;
      const float pb = proj_b[ch];
      for (int ntt = 0; ntt < 4; ++ntt) {
        const int t = ntt * 16 + llo;
        ob[(size_t)ch * 65536 + (y0 + (t >> 3)) * 256 + x0 + (t & 7)] =
            pacc[mc][ntt][r] + pb;
      }
    }
}

extern "C" void kernel_launch(void* const* d_in, const int* in_sizes, int n_in,
                              void* d_out, int out_size, void* d_ws, size_t ws_size,
                              hipStream_t stream) {
  const float* x = (const float*)d_in[0];
  const float* qkv_w = (const float*)d_in[1];
  const float* qkv_b = (const float*)d_in[2];
  const float* proj_w = (const float*)d_in[3];
  const float* proj_b = (const float*)d_in[4];
  const float* tbl = (const float*)d_in[5];
  const int* ridx = (const int*)d_in[6];
  float* out = (float*)d_out;

  char* ws = (char*)d_ws;
  short* wq = (short*)ws;                    // 98304 B: qkv_w bf16
  short* wp = (short*)(ws + 98304);          // 32768 B: proj_w bf16
  float* bias_frag = (float*)(ws + 131072);  // 65536 B: bias in C-frag order

  prep_kernel<<<64, 256, 0, stream>>>(qkv_w, proj_w, tbl, ridx, wq, wp, bias_frag);
  winattn_kernel<<<8192, 256, 0, stream>>>(x, qkv_b, proj_b, wq, wp, bias_frag, out);
}

// Round 3
// 379.800 us; speedup vs baseline: 1.0181x; 1.0181x over previous
//
#include <hip/hip_runtime.h>

typedef __attribute__((ext_vector_type(8))) short bf16x8;
typedef __attribute__((ext_vector_type(4))) float f32x4;
typedef __attribute__((ext_vector_type(2))) unsigned u32x2;

#define MFMA(a, b, c) __builtin_amdgcn_mfma_f32_16x16x32_bf16((a), (b), (c), 0, 0, 0)
#define Q_SCALE 0.17677669529663687f /* 32^-0.5 */
// XOR swizzle for 256B-row token-major tiles (XS / AO): 2-way banking max.
// NOTE: swizzle bits are address bits 4-6 -> any post-XOR add must stay
// below bit 4; otherwise recompute the full expression.
#define SWZ(t) ((((t) >> 2) & 7) << 4)

__device__ __forceinline__ short f2bf(float f) {
  union { float f; unsigned u; } c; c.f = f;
  unsigned u = c.u;
  return (short)((u + 0x7FFFu + ((u >> 16) & 1u)) >> 16);  // RNE
}

__device__ __forceinline__ unsigned cvtpk(float lo, float hi) {
  unsigned r;
  asm("v_cvt_pk_bf16_f32 %0, %1, %2" : "=v"(r) : "v"(lo), "v"(hi));
  return r;
}

// C-frag -> A/B-frag lane exchange (intra-wave, 4 lhi groups).
// pa = pack of k-tile 0 (2 dwords = 4 bf16, reg-run order), pb = k-tile 1.
// dest lane (llo,lhi) gets 8 consecutive k at k0 = lhi*8 from tile (lhi>>1).
__device__ __forceinline__ bf16x8 xch(unsigned pa0, unsigned pa1,
                                      unsigned pb0, unsigned pb1,
                                      int sA, int sB, int hi) {
  int a0 = __shfl((int)pa0, sA), b0 = __shfl((int)pb0, sA);
  int a1 = __shfl((int)pa1, sA), b1 = __shfl((int)pb1, sA);
  int a2 = __shfl((int)pa0, sB), b2 = __shfl((int)pb0, sB);
  int a3 = __shfl((int)pa1, sB), b3 = __shfl((int)pb1, sB);
  union { int u[4]; bf16x8 v; } r;
  r.u[0] = hi ? b0 : a0;
  r.u[1] = hi ? b1 : a1;
  r.u[2] = hi ? b2 : a2;
  r.u[3] = hi ? b3 : a3;
  return r.v;
}

// ---------------------------------------------------------------------------
// prep: bf16 weights (Q rows pre-scaled), scaled qkv bias, bias table gathered
// in TRANSPOSED C-frag order: rows = key j, cols = query i.
// ---------------------------------------------------------------------------
__global__ void prep_kernel(const float* __restrict__ qkv_w,
                            const float* __restrict__ qkv_b,
                            const float* __restrict__ proj_w,
                            const float* __restrict__ tbl,
                            const int* __restrict__ ridx,
                            short* __restrict__ wq, short* __restrict__ wp,
                            float* __restrict__ qb, float* __restrict__ bfr) {
  const int stride = gridDim.x * blockDim.x;
  const int tid = blockIdx.x * blockDim.x + threadIdx.x;
  for (int i = tid; i < 384 * 128; i += stride)
    wq[i] = f2bf(qkv_w[i] * (i < 128 * 128 ? Q_SCALE : 1.f));
  for (int i = tid; i < 128 * 128; i += stride) wp[i] = f2bf(proj_w[i]);
  for (int i = tid; i < 384; i += stride)
    qb[i] = qkv_b[i] * (i < 128 ? Q_SCALE : 1.f);
  for (int i = tid; i < 4 * 64 * 64; i += stride) {
    int reg = i & 3, it = (i >> 2) & 3, jt = (i >> 4) & 3;
    int l = (i >> 6) & 63, h = i >> 12;
    int qi = it * 16 + (l & 15);            // query (column)
    int kj = jt * 16 + (l >> 4) * 4 + reg;  // key (row)
    bfr[i] = tbl[ridx[qi * 64 + kj] * 4 + h];
  }
}

// ---------------------------------------------------------------------------
// fused window attention, register-resident QKV/P (wave = head).
// LDS: single 16 KB token-major [64][128] bf16 region, XOR-swizzled:
//   phase 0/1: XS (x tile);  phase 4/6: AO (attn output, pre-proj).
// 3 barriers total.
// ---------------------------------------------------------------------------
__global__ __launch_bounds__(256, 3) void winattn_kernel(
    const float* __restrict__ x, const float* __restrict__ proj_b,
    const short* __restrict__ wq, const short* __restrict__ wp,
    const float* __restrict__ qb, const float* __restrict__ bfr,
    float* __restrict__ out) {
  __shared__ __align__(16) char lds[16384];

  const int tid = threadIdx.x;
  const int w = tid >> 6;  // wave id == head
  const int l = tid & 63;
  const int llo = l & 15, lhi = l >> 4;
  const int sA = llo + ((lhi & 1) << 5);  // exchange source lanes
  const int sB = sA + 16;
  const int hi = lhi >> 1;

  // XCD-bijective swizzle (8192 % 8 == 0)
  const int bid = blockIdx.x;
  const int wid = (bid & 7) * 1024 + (bid >> 3);
  const int b = wid >> 10;
  const int wy = (wid >> 5) & 31, wx = wid & 31;
  const int y0 = wy * 8, x0 = wx * 8;

  // ---- Phase 0: global x (f32) -> XS bf16 [token][channel], swizzled
  const float* xb = x + (size_t)b * 128 * 65536;
#pragma unroll
  for (int k = 0; k < 8; ++k) {
    int u = tid + k * 256;
    int c = u >> 4, i = (u >> 1) & 7, j4 = u & 1;
    f32x4 v4 = *(const f32x4*)(xb + (size_t)c * 65536 + (y0 + i) * 256 + x0 + j4 * 4);
    int t0 = i * 8 + j4 * 4;
    int base = (t0 * 256 + c * 2) ^ SWZ(t0);  // t0..t0+3 share swizzle bits
    *(short*)(lds + base + 0) = f2bf(v4[0]);
    *(short*)(lds + base + 256) = f2bf(v4[1]);
    *(short*)(lds + base + 512) = f2bf(v4[2]);
    *(short*)(lds + base + 768) = f2bf(v4[3]);
  }
  __syncthreads();

  // ---- Phase 1: QKV GEMM, outputs packed bf16 in registers.
  // g 0,1 = Q tiles (C[o][t]); 2,3 = K tiles (C[o][t]); 4,5 = V tiles (C[t][d])
  unsigned pkq[2][4][2], pkk[2][4][2], pkv[2][4][2];
#pragma unroll
  for (int grp = 0; grp < 2; ++grp) {
    bf16x8 wf[3][4];
    f32x4 qb4[3];
    float bv[3];
#pragma unroll
    for (int gi = 0; gi < 3; ++gi) {
      const int g = grp * 3 + gi;
      const int rowbase = (g >> 1) * 128 + w * 32 + (g & 1) * 16;
#pragma unroll
      for (int ks = 0; ks < 4; ++ks)
        wf[gi][ks] = *(const bf16x8*)(wq + (rowbase + llo) * 128 + ks * 32 + lhi * 8);
      if (g < 4)
        qb4[gi] = *(const f32x4*)(qb + rowbase + lhi * 4);
      else
        bv[gi] = qb[rowbase + llo];
    }
#pragma unroll
    for (int tt = 0; tt < 4; ++tt) {
      bf16x8 xf[4];
      const int t = tt * 16 + llo;
#pragma unroll
      for (int ks = 0; ks < 4; ++ks)
        xf[ks] = *(const bf16x8*)(lds + ((t * 256 + ks * 64 + lhi * 16) ^ SWZ(t)));
#pragma unroll
      for (int gi = 0; gi < 3; ++gi) {
        const int g = grp * 3 + gi;
        f32x4 acc = {0.f, 0.f, 0.f, 0.f};
        if (g < 4) {
#pragma unroll
          for (int ks = 0; ks < 4; ++ks) acc = MFMA(wf[gi][ks], xf[ks], acc);
          unsigned d0 = cvtpk(acc[0] + qb4[gi][0], acc[1] + qb4[gi][1]);
          unsigned d1 = cvtpk(acc[2] + qb4[gi][2], acc[3] + qb4[gi][3]);
          if (g < 2) { pkq[g][tt][0] = d0; pkq[g][tt][1] = d1; }
          else       { pkk[g - 2][tt][0] = d0; pkk[g - 2][tt][1] = d1; }
        } else {
#pragma unroll
          for (int ks = 0; ks < 4; ++ks) acc = MFMA(xf[ks], wf[gi][ks], acc);
          pkv[g - 4][tt][0] = cvtpk(acc[0] + bv[gi], acc[1] + bv[gi]);
          pkv[g - 4][tt][1] = cvtpk(acc[2] + bv[gi], acc[3] + bv[gi]);
        }
      }
    }
  }
  __syncthreads();  // XS dead -> AO region writable later

  // ---- Build K A-frags (rows = key token over d) and V A-frags (rows = d over j)
  bf16x8 kf[4], va[2][2];
#pragma unroll
  for (int jt = 0; jt < 4; ++jt)
    kf[jt] = xch(pkk[0][jt][0], pkk[0][jt][1], pkk[1][jt][0], pkk[1][jt][1], sA, sB, hi);
#pragma unroll
  for (int vt = 0; vt < 2; ++vt)
#pragma unroll
    for (int ks = 0; ks < 2; ++ks)
      va[vt][ks] = xch(pkv[vt][2 * ks][0], pkv[vt][2 * ks][1],
                       pkv[vt][2 * ks + 1][0], pkv[vt][2 * ks + 1][1], sA, sB, hi);

  // ---- Phases 2-4 fused, streamed per query tile `it`
  const f32x4* bias4 = (const f32x4*)bfr + ((w * 64 + l) << 4);
#pragma unroll
  for (int it = 0; it < 4; ++it) {
    bf16x8 qf = xch(pkq[0][it][0], pkq[0][it][1], pkq[1][it][0], pkq[1][it][1], sA, sB, hi);
    f32x4 dots[4];
#pragma unroll
    for (int jt = 0; jt < 4; ++jt) {
      dots[jt] = bias4[jt * 4 + it];            // bias preloaded as accumulator
      dots[jt] = MFMA(kf[jt], qf, dots[jt]);    // C[j][i]: rows=key, cols=query
    }
    // softmax over key axis: 16 lane-local values + 2 cross-lhi shfls
    float m = dots[0][0];
#pragma unroll
    for (int jt = 0; jt < 4; ++jt)
#pragma unroll
      for (int r = 0; r < 4; ++r) m = fmaxf(m, dots[jt][r]);
    m = fmaxf(m, __shfl_xor(m, 16));
    m = fmaxf(m, __shfl_xor(m, 32));
    float p[4][4];
    float s = 0.f;
#pragma unroll
    for (int jt = 0; jt < 4; ++jt)
#pragma unroll
      for (int r = 0; r < 4; ++r) {
        p[jt][r] = __expf(dots[jt][r] - m);
        s += p[jt][r];
      }
    s += __shfl_xor(s, 16);
    s += __shfl_xor(s, 32);
    const float inv = 1.f / s;
    unsigned pk[4][2];
#pragma unroll
    for (int jt = 0; jt < 4; ++jt) {
      pk[jt][0] = cvtpk(p[jt][0], p[jt][1]);
      pk[jt][1] = cvtpk(p[jt][2], p[jt][3]);
    }
    bf16x8 pb0 = xch(pk[0][0], pk[0][1], pk[1][0], pk[1][1], sA, sB, hi);
    bf16x8 pb1 = xch(pk[2][0], pk[2][1], pk[3][0], pk[3][1], sA, sB, hi);
    // PV: C[d][t] (rows = d, cols = query token)
    f32x4 o0 = {0.f, 0.f, 0.f, 0.f}, o1 = {0.f, 0.f, 0.f, 0.f};
    o0 = MFMA(va[0][0], pb0, o0);
    o0 = MFMA(va[0][1], pb1, o0);
    o1 = MFMA(va[1][0], pb0, o1);
    o1 = MFMA(va[1][1], pb1, o1);
    // normalize + write AO[t][c] (c = head*32 + d), packed b64, swizzled.
    // Each 8B store's full address is computed BEFORE the XOR (bit 5 is a
    // swizzle bit, so "+32 after XOR" would be wrong — that was the R2 bug).
    const int t = it * 16 + llo;
    const int byte0 = (t * 256 + (w * 32 + lhi * 4) * 2) ^ SWZ(t);
    const int byte1 = (t * 256 + (w * 32 + 16 + lhi * 4) * 2) ^ SWZ(t);
    u32x2 w0, w1;
    w0.x = cvtpk(o0[0] * inv, o0[1] * inv);
    w0.y = cvtpk(o0[2] * inv, o0[3] * inv);
    w1.x = cvtpk(o1[0] * inv, o1[1] * inv);
    w1.y = cvtpk(o1[2] * inv, o1[3] * inv);
    *(u32x2*)(lds + byte0) = w0;
    *(u32x2*)(lds + byte1) = w1;
  }

  // ---- Phase 6: proj. A = wp rows (och over c), B = AO rows (t over c).
  bf16x8 wpf[2][4];
  f32x4 pb4[2];
#pragma unroll
  for (int ot = 0; ot < 2; ++ot) {
#pragma unroll
    for (int ks = 0; ks < 4; ++ks)
      wpf[ot][ks] = *(const bf16x8*)(wp + (w * 32 + ot * 16 + llo) * 128 + ks * 32 + lhi * 8);
    pb4[ot] = *(const f32x4*)(proj_b + w * 32 + ot * 16 + lhi * 4);
  }
  __syncthreads();  // AO complete

  float* ob = out + (size_t)b * 128 * 65536;
#pragma unroll
  for (int it = 0; it < 4; ++it) {
    const int t = it * 16 + llo;
    bf16x8 af[4];
#pragma unroll
    for (int ks = 0; ks < 4; ++ks)
      af[ks] = *(const bf16x8*)(lds + ((t * 256 + ks * 64 + lhi * 16) ^ SWZ(t)));
#pragma unroll
    for (int ot = 0; ot < 2; ++ot) {
      f32x4 acc = {0.f, 0.f, 0.f, 0.f};
#pragma unroll
      for (int ks = 0; ks < 4; ++ks) acc = MFMA(wpf[ot][ks], af[ks], acc);
#pragma unroll
      for (int r = 0; r < 4; ++r) {
        const int ch = w * 32 + ot * 16 + lhi * 4 + r;
        ob[(size_t)ch * 65536 + (y0 + (t >> 3)) * 256 + x0 + (t & 7)] =
            acc[r] + pb4[ot][r];
      }
    }
  }
}

extern "C" void kernel_launch(void* const* d_in, const int* in_sizes, int n_in,
                              void* d_out, int out_size, void* d_ws, size_t ws_size,
                              hipStream_t stream) {
  const float* x = (const float*)d_in[0];
  const float* qkv_w = (const float*)d_in[1];
  const float* qkv_b = (const float*)d_in[2];
  const float* proj_w = (const float*)d_in[3];
  const float* proj_b = (const float*)d_in[4];
  const float* tbl = (const float*)d_in[5];
  const int* ridx = (const int*)d_in[6];
  float* out = (float*)d_out;

  char* ws = (char*)d_ws;
  short* wq = (short*)ws;                    //      0 .. 98304: qkv_w bf16 (Q pre-scaled)
  short* wp = (short*)(ws + 98304);          //  98304 ..131072: proj_w bf16
  float* qb = (float*)(ws + 131072);         // 131072 ..132608: scaled qkv_b f32
  float* bfr = (float*)(ws + 132608);        // 132608 ..198144: bias, transposed frag order

  prep_kernel<<<64, 256, 0, stream>>>(qkv_w, qkv_b, proj_w, tbl, ridx, wq, wp, qb, bfr);
  winattn_kernel<<<8192, 256, 0, stream>>>(x, proj_b, wq, wp, qb, bfr, out);
}